// Round 11
// baseline (339.578 us; speedup 1.0000x reference)
//
#include <hip/hip_runtime.h>
#include <hip/hip_bf16.h>
#include <math.h>

typedef __bf16 bf16_8 __attribute__((ext_vector_type(8)));
typedef __bf16 bf16_4 __attribute__((ext_vector_type(4)));
typedef float f32x4 __attribute__((ext_vector_type(4)));

#define AS1 __attribute__((address_space(1)))
#define AS3 __attribute__((address_space(3)))

// (1/sqrt(64)) * log2(e): folded into Q at QKV-epilogue so attn scores are
// already in exp2 domain.
#define SCL_Q 0.18033688011112042f

// ---------------------------------------------------------------- LayerNorm (fp32 in -> bf16 out)
__global__ __launch_bounds__(256) void ln_kernel(
    const float* __restrict__ x, const float* __restrict__ g,
    const float* __restrict__ b, __hip_bfloat16* __restrict__ out, int cols) {
  const int row = blockIdx.x;
  const int t = threadIdx.x;
  float loc[3];
  float s = 0.f, s2 = 0.f;
#pragma unroll
  for (int i = 0; i < 3; ++i) {
    float v = x[(size_t)row * cols + t + i * 256];
    loc[i] = v;
    s += v;
    s2 += v * v;
  }
#pragma unroll
  for (int off = 32; off; off >>= 1) {
    s += __shfl_down(s, off);
    s2 += __shfl_down(s2, off);
  }
  __shared__ float red[2][4];
  const int lane = t & 63, w = t >> 6;
  if (lane == 0) {
    red[0][w] = s;
    red[1][w] = s2;
  }
  __syncthreads();
  s = red[0][0] + red[0][1] + red[0][2] + red[0][3];
  s2 = red[1][0] + red[1][1] + red[1][2] + red[1][3];
  const float mu = s / cols;
  const float var = s2 / cols - mu * mu;
  const float rs = rsqrtf(var + 1e-5f);
  __hip_bfloat16* orow = out + (size_t)row * cols;
#pragma unroll
  for (int i = 0; i < 3; ++i) {
    int c = t + i * 256;
    orow[c] = __hip_bfloat16((loc[i] - mu) * rs * g[c] + b[c]);
  }
}

// ---------------------------------------------------------------- fused split-K reduce + residual + LN2
__global__ __launch_bounds__(256) void reduce_ln(
    const float* __restrict__ x, const float* __restrict__ part, int nz,
    const float* __restrict__ bias, const float* __restrict__ g,
    const float* __restrict__ b, float* __restrict__ res,
    __hip_bfloat16* __restrict__ yout) {
  const int row = blockIdx.x;
  const int t = threadIdx.x;
  const size_t zstride = (size_t)4096 * 768;
  float loc[3];
  float s = 0.f, s2 = 0.f;
#pragma unroll
  for (int i = 0; i < 3; ++i) {
    const int c = t + i * 256;
    const size_t off = (size_t)row * 768 + c;
    float v = x[off] + bias[c];
    for (int z = 0; z < nz; ++z) v += part[(size_t)z * zstride + off];
    res[off] = v;
    loc[i] = v;
    s += v;
    s2 += v * v;
  }
#pragma unroll
  for (int off = 32; off; off >>= 1) {
    s += __shfl_down(s, off);
    s2 += __shfl_down(s2, off);
  }
  __shared__ float red[2][4];
  const int lane = t & 63, w = t >> 6;
  if (lane == 0) {
    red[0][w] = s;
    red[1][w] = s2;
  }
  __syncthreads();
  s = red[0][0] + red[0][1] + red[0][2] + red[0][3];
  s2 = red[1][0] + red[1][1] + red[1][2] + red[1][3];
  const float mu = s / 768.f;
  const float var = s2 / 768.f - mu * mu;
  const float rs = rsqrtf(var + 1e-5f);
#pragma unroll
  for (int i = 0; i < 3; ++i) {
    const int c = t + i * 256;
    yout[(size_t)row * 768 + c] = __hip_bfloat16((loc[i] - mu) * rs * g[c] + b[c]);
  }
}

// ---------------------------------------------------------------- fused split-K reduce into residual (final out)
__global__ __launch_bounds__(256) void reduce_out(
    const float* __restrict__ part, int nz, const float* __restrict__ bias,
    float* __restrict__ res) {
  const int row = blockIdx.x;
  const int t = threadIdx.x;
  const size_t zstride = (size_t)4096 * 768;
#pragma unroll
  for (int i = 0; i < 3; ++i) {
    const int c = t + i * 256;
    const size_t off = (size_t)row * 768 + c;
    float v = res[off] + bias[c];
    for (int z = 0; z < nz; ++z) v += part[(size_t)z * zstride + off];
    res[off] = v;
  }
}

// ---------------------------------------------------------------- fp32 -> bf16 weight conversion (fallback path)
__global__ __launch_bounds__(256) void cvt_multi(
    const float* __restrict__ sa, const float* __restrict__ sb,
    const float* __restrict__ sc, const float* __restrict__ sd,
    __hip_bfloat16* __restrict__ da, __hip_bfloat16* __restrict__ db,
    __hip_bfloat16* __restrict__ dc, __hip_bfloat16* __restrict__ dd) {
  const float* src;
  __hip_bfloat16* dst;
  if (blockIdx.y == 0) { src = sa; dst = da; }
  else if (blockIdx.y == 1) { src = sb; dst = db; }
  else if (blockIdx.y == 2) { src = sc; dst = dc; }
  else { src = sd; dst = dd; }
  const size_t i = ((size_t)blockIdx.x * 256 + threadIdx.x) * 4;
  float4 f = *(const float4*)(src + i);
  bf16_4 o;
  o[0] = (__bf16)f.x; o[1] = (__bf16)f.y; o[2] = (__bf16)f.z; o[3] = (__bf16)f.w;
  *(bf16_4*)((__bf16*)dst + i) = o;
}

// ---------------------------------------------------------------- all 6 weights -> bf16 in one launch
__global__ __launch_bounds__(256) void cvt_all(
    const float* __restrict__ wq, const float* __restrict__ wk,
    const float* __restrict__ wv, const float* __restrict__ wo,
    const float* __restrict__ w1, const float* __restrict__ w2,
    __hip_bfloat16* __restrict__ dA, __hip_bfloat16* __restrict__ dF) {
  const size_t EE = 589824, EF = 2359296;
  int bid = blockIdx.x;
  const float* src;
  __hip_bfloat16* dst;
  size_t off;
  if (bid < 2304) {
    const int m = bid / 576;
    off = (size_t)(bid - m * 576) * 1024;
    src = (m == 0) ? wq : (m == 1) ? wk : (m == 2) ? wv : wo;
    dst = dA + (size_t)m * EE;
  } else {
    bid -= 2304;
    const int m = bid / 2304;
    off = (size_t)(bid - m * 2304) * 1024;
    src = m ? w2 : w1;
    dst = dF + (size_t)m * EF;
  }
  const size_t i = off + (size_t)threadIdx.x * 4;
  float4 f = *(const float4*)(src + i);
  bf16_4 o;
  o[0] = (__bf16)f.x; o[1] = (__bf16)f.y; o[2] = (__bf16)f.z; o[3] = (__bf16)f.w;
  *(bf16_4*)((__bf16*)dst + i) = o;
}

// ---------------------------------------------------------------- V pre-transpose + key-permute (frozen)
// Also zeroes the attn work-counter (block 0).
__global__ __launch_bounds__(256) void transpose_v(
    const __hip_bfloat16* __restrict__ v, __hip_bfloat16* __restrict__ vt,
    int* __restrict__ ctr) {
  const int S = 2048, E = 768, H = 12;
  if (blockIdx.x == 0 && blockIdx.y == 0 && threadIdx.x == 0) *ctr = 0;
  const int s0 = blockIdx.x * 64;
  const int bh = blockIdx.y;
  const int b = bh / H, h = bh - b * H;
  __shared__ __align__(16) __bf16 T[64 * 72];
  const int tid = threadIdx.x;
#pragma unroll
  for (int u = 0; u < 2; ++u) {
    int i = tid + u * 256;
    int sr = i >> 3, c = i & 7;
    *(bf16_8*)(&T[sr * 72 + c * 8]) =
        *(const bf16_8*)(v + ((size_t)b * S + s0 + sr) * E + h * 64 + c * 8);
  }
  __syncthreads();
#pragma unroll
  for (int u = 0; u < 2; ++u) {
    int i = tid + u * 256;
    int dr = i >> 3, kc = i & 7;
    bf16_8 o;
#pragma unroll
    for (int e = 0; e < 8; ++e) {
      int k = 32 * (kc >> 2) + 16 * (e >> 2) + 4 * (kc & 3) + (e & 3);
      o[e] = T[k * 72 + dr];
    }
    *(bf16_8*)(vt + ((size_t)bh * 64 + dr) * S + s0 + kc * 8) = o;
  }
}

// ---------------------------------------------------------------- GEMM (frozen from round 10)
template <int MODE, bool BF32>
__global__ __launch_bounds__(256) void gemm_bt(
    const __hip_bfloat16* __restrict__ A, const void* __restrict__ Bx,
    const float* __restrict__ bias, void* __restrict__ out,
    int M, int N, int K, int lda, int ldb, int ldout) {
  constexpr int BM = 128, BN = 128, BK = 64;
  constexpr int LDBP = BF32 ? 72 : BK;
  __shared__ __align__(16) __bf16 As[BM * BK];
  __shared__ __align__(16) __bf16 Bs[BN * LDBP];
  const int tid = threadIdx.x;
  const int m0 = blockIdx.y * BM;
  const int n0 = blockIdx.x * BN;
  const int wave = tid >> 6;
  const int lane = tid & 63;
  const int quad = lane >> 4;
  const int l16 = lane & 15;
  const int wm = (wave & 1) * 64;
  const int wn = (wave >> 1) * 64;

  int kbase = 0, kcnt = K;
  if constexpr (MODE == 2 || MODE == 3) {
    kcnt = K / gridDim.z;
    kbase = blockIdx.z * kcnt;
  }

  const int srow = lane >> 3;
  const int scol = ((lane & 7) ^ (srow & 7)) * 8;
  const __hip_bfloat16* Ap = A + (size_t)(m0 + wave * 8 + srow) * lda + kbase + scol;
  const __hip_bfloat16* Bpb = nullptr;
  const float* Bpf = nullptr;
  if constexpr (BF32)
    Bpf = (const float*)Bx;
  else
    Bpb = (const __hip_bfloat16*)Bx + (size_t)(n0 + wave * 8 + srow) * ldb + kbase + scol;

  f32x4 acc[4][4] = {};

  for (int k0 = 0; k0 < kcnt; k0 += BK) {
    __syncthreads();
#pragma unroll
    for (int u = 0; u < 4; ++u) {
      __builtin_amdgcn_global_load_lds(
          (const AS1 void*)(Ap + (size_t)(u * 32) * lda + k0),
          (AS3 void*)(&As[(u * 32 + wave * 8) * BK]), 16, 0, 0);
      if constexpr (!BF32)
        __builtin_amdgcn_global_load_lds(
            (const AS1 void*)(Bpb + (size_t)(u * 32) * ldb + k0),
            (AS3 void*)(&Bs[(u * 32 + wave * 8) * BK]), 16, 0, 0);
    }
    if constexpr (BF32) {
#pragma unroll
      for (int u = 0; u < 4; ++u) {
        int c = u * 256 + tid;
        int row = c >> 3, kc = c & 7;
        const float* src = Bpf + (size_t)(n0 + row) * ldb + kbase + k0 + kc * 8;
        float4 f0 = *(const float4*)src;
        float4 f1 = *(const float4*)(src + 4);
        bf16_8 bv;
        bv[0] = (__bf16)f0.x; bv[1] = (__bf16)f0.y; bv[2] = (__bf16)f0.z; bv[3] = (__bf16)f0.w;
        bv[4] = (__bf16)f1.x; bv[5] = (__bf16)f1.y; bv[6] = (__bf16)f1.z; bv[7] = (__bf16)f1.w;
        *(bf16_8*)(&Bs[row * LDBP + kc * 8]) = bv;
      }
    }
    __syncthreads();
#pragma unroll
    for (int kk = 0; kk < 2; ++kk) {
      bf16_8 af[4], bfr[4];
#pragma unroll
      for (int i = 0; i < 4; ++i)
        af[i] = *(const bf16_8*)(
            &As[(wm + i * 16 + l16) * BK + (((kk * 4 + quad) ^ (l16 & 7)) * 8)]);
#pragma unroll
      for (int j = 0; j < 4; ++j) {
        if constexpr (BF32)
          bfr[j] = *(const bf16_8*)(&Bs[(wn + j * 16 + l16) * LDBP + kk * 32 + quad * 8]);
        else
          bfr[j] = *(const bf16_8*)(
              &Bs[(wn + j * 16 + l16) * BK + (((kk * 4 + quad) ^ (l16 & 7)) * 8)]);
      }
#pragma unroll
      for (int i = 0; i < 4; ++i)
#pragma unroll
        for (int j = 0; j < 4; ++j)
          acc[i][j] =
              __builtin_amdgcn_mfma_f32_16x16x32_bf16(af[i], bfr[j], acc[i][j], 0, 0, 0);
    }
  }

#pragma unroll
  for (int i = 0; i < 4; ++i) {
#pragma unroll
    for (int j = 0; j < 4; ++j) {
#pragma unroll
      for (int r = 0; r < 4; ++r) {
        const int row = m0 + wm + i * 16 + quad * 4 + r;
        const int col = n0 + wn + j * 16 + l16;
        const float v = acc[i][j][r];
        if constexpr (MODE == 0) {
          const int tsel = n0 / 768;
          const size_t idx = ((size_t)tsel * M + row) * 768 + (col - tsel * 768);
          const float vs = (tsel == 0) ? v * SCL_Q : v;  // pre-scale Q slot
          ((__hip_bfloat16*)out)[idx] = __hip_bfloat16(vs);
        } else if constexpr (MODE == 1) {
          float tt = v + bias[col];
          float gl = 0.5f * tt * (1.0f + erff(tt * 0.70710678118654752f));
          ((__hip_bfloat16*)out)[(size_t)row * ldout + col] = __hip_bfloat16(gl);
        } else if constexpr (MODE == 2) {
          float add = v + ((blockIdx.z == 0 && bias) ? bias[col] : 0.f);
          atomicAdd((float*)out + (size_t)row * 768 + col, add);
        } else {
          ((float*)out)[(size_t)blockIdx.z * M * 768 + (size_t)row * 768 + col] = v;
        }
      }
    }
  }
}

// ---------------------------------------------------------------- work counter (fallback path only)
__global__ void zero_ctr(int* __restrict__ c) {
  if (threadIdx.x == 0) *c = 0;
}

// ---------------------------------------------------------------- MFMA flash attention, v7: uniform 8-tile KV chunks
// Inner math frozen (in-reg P, exp2, defer-max, single-buf K + dbuf V^T).
// Every qblk>=8 splits into ceil((qblk+1)/8) parts of <=8 tiles; each part writes
// unnormalized O^T + (m,l); attn_combine (variable np<=4) merges. Longest serial
// chain: 16 -> 8 tiles. Every part has >=1 unmasked key per q-row (non-last parts
// end before q0; last part starts <= q0), so l>0 always.
#define ALDP 72
// 80-unit schedule (qblk, part), parts sorted by descending tile count.
// part 0..3 = 8-tile chunk index (kbgn = part*8); part 7 = full range (qblk<8).
__device__ __constant__ signed char UQ[80] = {
    8, 9, 10, 11, 12, 13, 14, 15, 15, 16, 16, 17, 17, 18, 18, 19,
    19, 20, 20, 21, 21, 22, 22, 23, 23, 23, 24, 24, 24, 25, 25, 25,
    26, 26, 26, 27, 27, 27, 28, 28, 28, 29, 29, 29, 30, 30, 30, 31,
    31, 31, 31, 7, 14, 22, 30, 6, 13, 21, 29, 5, 12, 20, 28, 4,
    11, 19, 27, 3, 10, 18, 26, 2, 9, 17, 25, 1, 8, 16, 24, 0};
__device__ __constant__ signed char UP[80] = {
    0, 0, 0, 0, 0, 0, 0, 0, 1, 0, 1, 0, 1, 0, 1, 0,
    1, 0, 1, 0, 1, 0, 1, 0, 1, 2, 0, 1, 2, 0, 1, 2,
    0, 1, 2, 0, 1, 2, 0, 1, 2, 0, 1, 2, 0, 1, 2, 0,
    1, 2, 3, 7, 1, 2, 3, 7, 1, 2, 3, 7, 1, 2, 3, 7,
    1, 2, 3, 7, 1, 2, 3, 7, 1, 2, 3, 7, 1, 2, 3, 7};

template <bool PRE_T, bool SPLIT>
__global__ __launch_bounds__(256) void attn_mfma(
    const __hip_bfloat16* __restrict__ qb, const __hip_bfloat16* __restrict__ kb,
    const __hip_bfloat16* __restrict__ vb, __hip_bfloat16* __restrict__ ob,
    float* __restrict__ po, float* __restrict__ pml, int* __restrict__ ctr) {
  const int S = 2048, H = 12, E = 768;
  const int tid = threadIdx.x;
  const int wave = tid >> 6;
  const int lane = tid & 63;
  const int quad = lane >> 4;
  const int l16 = lane & 15;

  __shared__ __align__(16) __bf16 Ks[64 * 64];     // single-buffer K, swizzled
  __shared__ __align__(16) __bf16 Vt[2][64 * 64];  // dbuf V^T (key-permuted), swizzled
  __shared__ int task;
  __bf16* ep = &Vt[0][0] + wave * 16 * ALDP;  // epilogue buffer aliases Vt

  const int srow8 = lane >> 3;
  const int csrc = ((lane & 7) ^ srow8) * 8;
  const int NTASK = SPLIT ? 24 * 80 : 24 * 32;

  for (;;) {
    if (tid == 0) task = atomicAdd(ctr, 1);
    __syncthreads();
    const int t = task;
    if (t >= NTASK) return;
    int qblk, part, bh;
    if constexpr (SPLIT) {
      const int unit = t / 24;
      bh = t - unit * 24;
      qblk = UQ[unit];
      part = UP[unit];
    } else {
      qblk = 31 - (t / 24);
      bh = t - (t / 24) * 24;
      part = 7;
    }
    const int b = bh / H, h = bh - b * H;
    const int q0 = qblk * 64;
    const int qw = q0 + wave * 16;
    const size_t base = (size_t)b * S * E + (size_t)h * 64;
    const bool prt = SPLIT && part != 7;
    const int kbgn = prt ? part * 8 : 0;
    int kend = qblk + 1;
    if (prt && kbgn + 8 < kend) kend = kbgn + 8;

    auto STAGE_K = [&](int kts) {
      const int k0s = kts * 64;
#pragma unroll
      for (int u = 0; u < 2; ++u) {
        const int trow = wave * 16 + u * 8;
        __builtin_amdgcn_global_load_lds(
            (const AS1 void*)(kb + base + (size_t)(k0s + trow + srow8) * E + csrc),
            (AS3 void*)(&Ks[trow * 64]), 16, 0, 0);
      }
    };
    auto STAGE_V = [&](int kts, int buf) {
      const int k0s = kts * 64;
      if constexpr (PRE_T) {
#pragma unroll
        for (int u = 0; u < 2; ++u) {
          const int trow = wave * 16 + u * 8;
          __builtin_amdgcn_global_load_lds(
              (const AS1 void*)(vb + ((size_t)(bh * 64 + trow + srow8)) * S + k0s + csrc),
              (AS3 void*)(&Vt[buf][trow * 64]), 16, 0, 0);
        }
      } else {
#pragma unroll
        for (int u = 0; u < 2; ++u) {
          int i = tid + u * 256;
          int kr = i & 63, dq = i >> 6;
          bf16_8 vv = *(const bf16_8*)(vb + base + (size_t)(k0s + kr) * E + dq * 8);
          const int c = 32 * (kr >> 5) + 8 * ((kr >> 2) & 3) + 4 * ((kr >> 4) & 1) + (kr & 3);
#pragma unroll
          for (int j = 0; j < 8; ++j) {
            int drow = dq * 8 + j;
            Vt[buf][drow * 64 + (((c >> 3) ^ (drow & 7)) * 8) + (c & 7)] = vv[j];
          }
        }
      }
    };

    bf16_8 qf[2];
#pragma unroll
    for (int s = 0; s < 2; ++s)
      qf[s] = *(const bf16_8*)(qb + base + (size_t)(qw + l16) * E + s * 32 + quad * 8);

    f32x4 o[4] = {};
    float mq = -1e30f, lq = 0.f;

    STAGE_K(kbgn);
    STAGE_V(kbgn, 0);
    __syncthreads();
    int cur = 0;

    for (int kt = kbgn; kt < kend; ++kt) {
      const int k0 = kt * 64;

      // S^T = K·Q^T (already exp2-domain-scaled via Q)
      f32x4 sc[4] = {};
      __builtin_amdgcn_s_setprio(1);
#pragma unroll
      for (int jj = 0; jj < 4; ++jj)
#pragma unroll
        for (int s = 0; s < 2; ++s) {
          bf16_8 kf = *(const bf16_8*)(
              &Ks[(jj * 16 + l16) * 64 + (((s * 4 + quad) ^ (l16 & 7)) * 8)]);
          sc[jj] = __builtin_amdgcn_mfma_f32_16x16x32_bf16(kf, qf[s], sc[jj], 0, 0, 0);
        }
      __builtin_amdgcn_s_setprio(0);

      __syncthreads();  // #1: all waves done reading Ks
      if (kt + 1 < kend) {
        STAGE_K(kt + 1);
        STAGE_V(kt + 1, cur ^ 1);
      }

      // causal mask on diagonal tile only (only the last part reaches it)
      if (kt == qblk) {
#pragma unroll
        for (int jj = 0; jj < 4; ++jj)
#pragma unroll
          for (int r = 0; r < 4; ++r)
            if ((k0 + jj * 16 + quad * 4 + r) > (qw + l16)) sc[jj][r] = -1e30f;
      }
      // per-query tile max (tree + 2 shuffles)
      float mj[4];
#pragma unroll
      for (int jj = 0; jj < 4; ++jj)
        mj[jj] = fmaxf(fmaxf(sc[jj][0], sc[jj][1]), fmaxf(sc[jj][2], sc[jj][3]));
      float pmax = fmaxf(fmaxf(mj[0], mj[1]), fmaxf(mj[2], mj[3]));
      pmax = fmaxf(pmax, __shfl_xor(pmax, 16));
      pmax = fmaxf(pmax, __shfl_xor(pmax, 32));
      // defer-max: only rescale when some lane's max rose past mq + 11.5 bits
      if (!__all(pmax <= mq + 11.5f)) {
        const float mn = fmaxf(mq, pmax);
        const float corr = exp2f(mq - mn);
        mq = mn;
        lq *= corr;
#pragma unroll
        for (int nt2 = 0; nt2 < 4; ++nt2)
#pragma unroll
          for (int r = 0; r < 4; ++r) o[nt2][r] *= corr;
      }
      // exp2 + tree sum
      float sj[4];
#pragma unroll
      for (int jj = 0; jj < 4; ++jj) {
#pragma unroll
        for (int r = 0; r < 4; ++r) sc[jj][r] = exp2f(sc[jj][r] - mq);
        sj[jj] = (sc[jj][0] + sc[jj][1]) + (sc[jj][2] + sc[jj][3]);
      }
      float sum = (sj[0] + sj[1]) + (sj[2] + sj[3]);
      sum += __shfl_xor(sum, 16);
      sum += __shfl_xor(sum, 32);
      lq += sum;

      // P fragments in-register (key-permuted to match vt layout)
      bf16_8 pf[2];
#pragma unroll
      for (int s = 0; s < 2; ++s)
#pragma unroll
        for (int r = 0; r < 4; ++r) {
          pf[s][r] = (__bf16)sc[2 * s][r];
          pf[s][4 + r] = (__bf16)sc[2 * s + 1][r];
        }

      // O^T += V^T·P^T
      __builtin_amdgcn_s_setprio(1);
#pragma unroll
      for (int s = 0; s < 2; ++s)
#pragma unroll
        for (int dt = 0; dt < 4; ++dt) {
          bf16_8 vf = *(const bf16_8*)(
              &Vt[cur][(dt * 16 + l16) * 64 + (((s * 4 + quad) ^ (l16 & 7)) * 8)]);
          o[dt] = __builtin_amdgcn_mfma_f32_16x16x32_bf16(vf, pf[s], o[dt], 0, 0, 0);
        }
      __builtin_amdgcn_s_setprio(0);

      __syncthreads();  // #2: drains K/V staging; Vt[cur] free
      cur ^= 1;
    }

    if (prt) {
      // unnormalized O^T partial [d][q] + (m,l); slot = bh*24 + (qblk-8)
      const int slot = bh * 24 + (qblk - 8);
      float* poT = po + (size_t)slot * 16384 + part * 4096;
      const int ql = wave * 16 + l16;
#pragma unroll
      for (int dt = 0; dt < 4; ++dt)
#pragma unroll
        for (int r = 0; r < 4; ++r)
          poT[(dt * 16 + quad * 4 + r) * 64 + ql] = o[dt][r];
      if (quad == 0) {
        pml[(size_t)slot * 512 + part * 128 + ql] = mq;
        pml[(size_t)slot * 512 + part * 128 + 64 + ql] = lq;
      }
    } else {
      const float inv = 1.f / lq;
#pragma unroll
      for (int dt = 0; dt < 4; ++dt) {
        bf16_4 o4;
#pragma unroll
        for (int r = 0; r < 4; ++r) o4[r] = (__bf16)(o[dt][r] * inv);
        *(bf16_4*)(&ep[l16 * ALDP + dt * 16 + quad * 4]) = o4;
      }
#pragma unroll
      for (int u = 0; u < 2; ++u) {
        int j = lane + u * 64;
        int ql = j >> 3, ch = j & 7;
        bf16_8 ov = *(const bf16_8*)(&ep[ql * ALDP + ch * 8]);
        *(bf16_8*)(ob + base + (size_t)(qw + ql) * E + ch * 8) = ov;
      }
    }
  }
}

// ---------------------------------------------------------------- combine variable-np KV partials (coalesced)
// grid = 576: cidx -> bh = cidx/24, qblk = 8 + cidx%24, np = qblk/8 + 1 (2..4).
__global__ __launch_bounds__(256) void attn_combine(
    const float* __restrict__ po, const float* __restrict__ pml,
    __hip_bfloat16* __restrict__ ob) {
  const int S = 2048, H = 12, E = 768;
  const int cidx = blockIdx.x;
  const int bh = cidx / 24;
  const int qblk = 8 + (cidx - bh * 24);
  const int np = qblk / 8 + 1;
  const int b = bh / H, h = bh - b * H;
  const int q0 = qblk * 64;
  const size_t base = (size_t)b * S * E + (size_t)h * 64;
  const float* PB = po + (size_t)cidx * 16384;
  const float* ML = pml + (size_t)cidx * 512;

  __shared__ float aw[4][64];
  __shared__ float dn[64];
  __shared__ float T[64 * 65];
  const int t = threadIdx.x;
  if (t < 64) {
    float ms = -1e30f;
    for (int p = 0; p < np; ++p) ms = fmaxf(ms, ML[p * 128 + t]);
    float den = 0.f;
    for (int p = 0; p < np; ++p) {
      const float e = exp2f(ML[p * 128 + t] - ms);
      aw[p][t] = e;
      den += e * ML[p * 128 + 64 + t];
    }
    dn[t] = 1.f / den;
  }
  __syncthreads();
  const int q = t & 63;
  const int w = t >> 6;
#pragma unroll
  for (int i = 0; i < 16; ++i) {
    const int d = w * 16 + i;
    float acc = 0.f;
    for (int p = 0; p < np; ++p) acc += aw[p][q] * PB[p * 4096 + d * 64 + q];
    T[q * 65 + d] = acc * dn[q];
  }
  __syncthreads();
  const int c8 = t & 7;
  const int qr = t >> 3;
#pragma unroll
  for (int p = 0; p < 2; ++p) {
    const int qq = qr + p * 32;
    bf16_8 ov;
#pragma unroll
    for (int j = 0; j < 8; ++j) ov[j] = (__bf16)T[qq * 65 + c8 * 8 + j];
    *(bf16_8*)(ob + base + (size_t)(q0 + qq) * E + c8 * 8) = ov;
  }
}

// ---------------------------------------------------------------- launch
extern "C" void kernel_launch(void* const* d_in, const int* in_sizes, int n_in,
                              void* d_out, int out_size, void* d_ws, size_t ws_size,
                              hipStream_t stream) {
  const int Bv = 2, S = 2048, E = 768, FF = 3072;
  const int M = Bv * S;  // 4096
  const size_t ME = (size_t)M * E;
  const size_t EE = (size_t)E * E;
  const size_t EF = (size_t)E * FF;

  const float* x = (const float*)d_in[0];
  const float* wq = (const float*)d_in[1];
  const float* wk = (const float*)d_in[2];
  const float* wv = (const float*)d_in[3];
  const float* wo = (const float*)d_in[4];
  const float* bo = (const float*)d_in[5];
  const float* w1 = (const float*)d_in[6];
  const float* b1 = (const float*)d_in[7];
  const float* w2 = (const float*)d_in[8];
  const float* b2 = (const float*)d_in[9];
  const float* gamma = (const float*)d_in[10];
  const float* beta = (const float*)d_in[11];

  // ws: [ctr+256B][s0..s4: 5×ME bf16][s5: w1|w2 bf16 2×EF][pp: 4×ME fp32 = 50.3MB]
  // Attention phase time-shares pp: vt (6.29MB) + po (576×4×16KB = 37.75MB) +
  // pml (1.18MB) = 45.2MB <= 50.3MB. All dead before GEMM partials reuse pp.
  int* ctr = (int*)d_ws;
  __hip_bfloat16* slot = (__hip_bfloat16*)((char*)d_ws + 256);
  __hip_bfloat16* s0 = slot;
  __hip_bfloat16* s1 = slot + ME;
  __hip_bfloat16* s4 = slot + 4 * ME;
  __hip_bfloat16* s5 = slot + 5 * ME;
  float* pp = (float*)(slot + 5 * ME + 2 * EF);
  __hip_bfloat16* vt = (__hip_bfloat16*)pp;
  float* po = (float*)((char*)pp + ME * sizeof(__hip_bfloat16));
  float* pml = po + (size_t)576 * 16384;
  float* res = (float*)d_out;

  const size_t need_mid = 256 + (5 * ME + 2 * EF) * sizeof(__hip_bfloat16);
  const size_t need_full = need_mid + 4 * ME * sizeof(float);
  const bool full = ws_size >= need_full;
  const bool mid = ws_size >= need_mid;

  // 0. weights -> bf16 (one launch when s5 exists)
  if (mid)
    cvt_all<<<6912, 256, 0, stream>>>(wq, wk, wv, wo, w1, w2, s4, s5);
  else
    cvt_multi<<<dim3(EE / 1024, 4), 256, 0, stream>>>(
        wq, wk, wv, wo, s4, s4 + EE, s4 + 2 * EE, s4 + 3 * EE);
  // 1. LN1
  ln_kernel<<<M, 256, 0, stream>>>(x, gamma, beta, s0, E);
  // 2. fused Q/K/V projection -> s1,s2,s3 (Q pre-scaled by SCL_Q)
  gemm_bt<0, false><<<dim3(18, 32), 256, 0, stream>>>(s0, s4, nullptr, s1, M, 2304, E, E, E, 0);
  // 3. causal flash attention -> s0 (8-tile chunks -> po/pml, combined after)
  if (full) {
    transpose_v<<<dim3(32, 24), 256, 0, stream>>>(s1 + 2 * ME, vt, ctr);  // also zeroes ctr
    attn_mfma<true, true><<<1536, 256, 0, stream>>>(s1, s1 + ME, vt, s0, po, pml, ctr);
    attn_combine<<<576, 256, 0, stream>>>(po, pml, s0);
  } else {
    zero_ctr<<<1, 64, 0, stream>>>(ctr);
    attn_mfma<false, false><<<768, 256, 0, stream>>>(
        s1, s1 + ME, s1 + 2 * ME, s0, nullptr, nullptr, ctr);
  }

  if (full) {
    // 4. attn-proj partials z=4
    gemm_bt<3, false><<<dim3(6, 32, 4), 256, 0, stream>>>(
        s0, s4 + 3 * EE, nullptr, pp, M, E, E, E, E, 0);
    // 5. res = x + Σpp + bo; y = LN2(res) -> s0
    reduce_ln<<<M, 256, 0, stream>>>(x, pp, 4, bo, gamma, beta, res, s0);
    // 6. FFN up + GELU -> s1..s4
    gemm_bt<1, false><<<dim3(24, 32), 256, 0, stream>>>(s0, s5, b1, s1, M, FF, E, E, E, FF);
    // 7. FFN down partials z=4
    gemm_bt<3, false><<<dim3(6, 32, 4), 256, 0, stream>>>(
        s1, s5 + EF, nullptr, pp, M, E, FF, FF, FF, 0);
    // 8. out = res + Σpp + b2
    reduce_out<<<M, 256, 0, stream>>>(pp, 4, b2, res);
  } else {
    hipMemcpyAsync(d_out, x, ME * sizeof(float), hipMemcpyDeviceToDevice, stream);
    gemm_bt<2, false><<<dim3(6, 32, 2), 256, 0, stream>>>(
        s0, s4 + 3 * EE, bo, res, M, E, E, E, E, 0);
    ln_kernel<<<M, 256, 0, stream>>>(res, gamma, beta, s0, E);
    if (mid) {
      gemm_bt<1, false><<<dim3(24, 32), 256, 0, stream>>>(s0, s5, b1, s1, M, FF, E, E, E, FF);
      gemm_bt<2, false><<<dim3(6, 32, 4), 256, 0, stream>>>(
          s1, s5 + EF, b2, res, M, E, FF, FF, FF, 0);
    } else {
      gemm_bt<1, true><<<dim3(24, 32), 256, 0, stream>>>(s0, w1, b1, s1, M, FF, E, E, E, FF);
      cvt_multi<<<dim3(EF / 1024, 1), 256, 0, stream>>>(
          w2, nullptr, nullptr, nullptr, s0, nullptr, nullptr, nullptr);
      gemm_bt<2, false><<<dim3(6, 32, 4), 256, 0, stream>>>(
          s1, s0, b2, res, M, E, FF, FF, FF, 0);
    }
  }
}

// Round 12
// 301.772 us; speedup vs baseline: 1.1253x; 1.1253x over previous
//
#include <hip/hip_runtime.h>
#include <hip/hip_bf16.h>
#include <math.h>

typedef __bf16 bf16_8 __attribute__((ext_vector_type(8)));
typedef __bf16 bf16_4 __attribute__((ext_vector_type(4)));
typedef float f32x4 __attribute__((ext_vector_type(4)));

#define AS1 __attribute__((address_space(1)))
#define AS3 __attribute__((address_space(3)))

// (1/sqrt(64)) * log2(e): folded into Q at QKV-epilogue so attn scores are
// already in exp2 domain.
#define SCL_Q 0.18033688011112042f

// ---------------------------------------------------------------- LayerNorm (fp32 in -> bf16 out)
__global__ __launch_bounds__(256) void ln_kernel(
    const float* __restrict__ x, const float* __restrict__ g,
    const float* __restrict__ b, __hip_bfloat16* __restrict__ out, int cols) {
  const int row = blockIdx.x;
  const int t = threadIdx.x;
  float loc[3];
  float s = 0.f, s2 = 0.f;
#pragma unroll
  for (int i = 0; i < 3; ++i) {
    float v = x[(size_t)row * cols + t + i * 256];
    loc[i] = v;
    s += v;
    s2 += v * v;
  }
#pragma unroll
  for (int off = 32; off; off >>= 1) {
    s += __shfl_down(s, off);
    s2 += __shfl_down(s2, off);
  }
  __shared__ float red[2][4];
  const int lane = t & 63, w = t >> 6;
  if (lane == 0) {
    red[0][w] = s;
    red[1][w] = s2;
  }
  __syncthreads();
  s = red[0][0] + red[0][1] + red[0][2] + red[0][3];
  s2 = red[1][0] + red[1][1] + red[1][2] + red[1][3];
  const float mu = s / cols;
  const float var = s2 / cols - mu * mu;
  const float rs = rsqrtf(var + 1e-5f);
  __hip_bfloat16* orow = out + (size_t)row * cols;
#pragma unroll
  for (int i = 0; i < 3; ++i) {
    int c = t + i * 256;
    orow[c] = __hip_bfloat16((loc[i] - mu) * rs * g[c] + b[c]);
  }
}

// ---------------------------------------------------------------- fused split-K reduce into residual (final out)
__global__ __launch_bounds__(256) void reduce_out(
    const float* __restrict__ part, int nz, const float* __restrict__ bias,
    float* __restrict__ res) {
  const int row = blockIdx.x;
  const int t = threadIdx.x;
  const size_t zstride = (size_t)4096 * 768;
#pragma unroll
  for (int i = 0; i < 3; ++i) {
    const int c = t + i * 256;
    const size_t off = (size_t)row * 768 + c;
    float v = res[off] + bias[c];
    for (int z = 0; z < nz; ++z) v += part[(size_t)z * zstride + off];
    res[off] = v;
  }
}

// ---------------------------------------------------------------- fp32 -> bf16 weight conversion (fallback path)
__global__ __launch_bounds__(256) void cvt_multi(
    const float* __restrict__ sa, const float* __restrict__ sb,
    const float* __restrict__ sc, const float* __restrict__ sd,
    __hip_bfloat16* __restrict__ da, __hip_bfloat16* __restrict__ db,
    __hip_bfloat16* __restrict__ dc, __hip_bfloat16* __restrict__ dd) {
  const float* src;
  __hip_bfloat16* dst;
  if (blockIdx.y == 0) { src = sa; dst = da; }
  else if (blockIdx.y == 1) { src = sb; dst = db; }
  else if (blockIdx.y == 2) { src = sc; dst = dc; }
  else { src = sd; dst = dd; }
  const size_t i = ((size_t)blockIdx.x * 256 + threadIdx.x) * 4;
  float4 f = *(const float4*)(src + i);
  bf16_4 o;
  o[0] = (__bf16)f.x; o[1] = (__bf16)f.y; o[2] = (__bf16)f.z; o[3] = (__bf16)f.w;
  *(bf16_4*)((__bf16*)dst + i) = o;
}

// ---------------------------------------------------------------- all 6 weights -> bf16 in one launch
__global__ __launch_bounds__(256) void cvt_all(
    const float* __restrict__ wq, const float* __restrict__ wk,
    const float* __restrict__ wv, const float* __restrict__ wo,
    const float* __restrict__ w1, const float* __restrict__ w2,
    __hip_bfloat16* __restrict__ dA, __hip_bfloat16* __restrict__ dF) {
  const size_t EE = 589824, EF = 2359296;
  int bid = blockIdx.x;
  const float* src;
  __hip_bfloat16* dst;
  size_t off;
  if (bid < 2304) {
    const int m = bid / 576;
    off = (size_t)(bid - m * 576) * 1024;
    src = (m == 0) ? wq : (m == 1) ? wk : (m == 2) ? wv : wo;
    dst = dA + (size_t)m * EE;
  } else {
    bid -= 2304;
    const int m = bid / 2304;
    off = (size_t)(bid - m * 2304) * 1024;
    src = m ? w2 : w1;
    dst = dF + (size_t)m * EF;
  }
  const size_t i = off + (size_t)threadIdx.x * 4;
  float4 f = *(const float4*)(src + i);
  bf16_4 o;
  o[0] = (__bf16)f.x; o[1] = (__bf16)f.y; o[2] = (__bf16)f.z; o[3] = (__bf16)f.w;
  *(bf16_4*)((__bf16*)dst + i) = o;
}

// ---------------------------------------------------------------- V pre-transpose + key-permute (frozen)
// Also zeroes the attn work-counter (block 0).
__global__ __launch_bounds__(256) void transpose_v(
    const __hip_bfloat16* __restrict__ v, __hip_bfloat16* __restrict__ vt,
    int* __restrict__ ctr) {
  const int S = 2048, E = 768, H = 12;
  if (blockIdx.x == 0 && blockIdx.y == 0 && threadIdx.x == 0) *ctr = 0;
  const int s0 = blockIdx.x * 64;
  const int bh = blockIdx.y;
  const int b = bh / H, h = bh - b * H;
  __shared__ __align__(16) __bf16 T[64 * 72];
  const int tid = threadIdx.x;
#pragma unroll
  for (int u = 0; u < 2; ++u) {
    int i = tid + u * 256;
    int sr = i >> 3, c = i & 7;
    *(bf16_8*)(&T[sr * 72 + c * 8]) =
        *(const bf16_8*)(v + ((size_t)b * S + s0 + sr) * E + h * 64 + c * 8);
  }
  __syncthreads();
#pragma unroll
  for (int u = 0; u < 2; ++u) {
    int i = tid + u * 256;
    int dr = i >> 3, kc = i & 7;
    bf16_8 o;
#pragma unroll
    for (int e = 0; e < 8; ++e) {
      int k = 32 * (kc >> 2) + 16 * (e >> 2) + 4 * (kc & 3) + (e & 3);
      o[e] = T[k * 72 + dr];
    }
    *(bf16_8*)(vt + ((size_t)bh * 64 + dr) * S + s0 + kc * 8) = o;
  }
}

// ---------------------------------------------------------------- GEMM (frozen from round 10)
template <int MODE, bool BF32>
__global__ __launch_bounds__(256) void gemm_bt(
    const __hip_bfloat16* __restrict__ A, const void* __restrict__ Bx,
    const float* __restrict__ bias, void* __restrict__ out,
    int M, int N, int K, int lda, int ldb, int ldout) {
  constexpr int BM = 128, BN = 128, BK = 64;
  constexpr int LDBP = BF32 ? 72 : BK;
  __shared__ __align__(16) __bf16 As[BM * BK];
  __shared__ __align__(16) __bf16 Bs[BN * LDBP];
  const int tid = threadIdx.x;
  const int m0 = blockIdx.y * BM;
  const int n0 = blockIdx.x * BN;
  const int wave = tid >> 6;
  const int lane = tid & 63;
  const int quad = lane >> 4;
  const int l16 = lane & 15;
  const int wm = (wave & 1) * 64;
  const int wn = (wave >> 1) * 64;

  int kbase = 0, kcnt = K;
  if constexpr (MODE == 2 || MODE == 3) {
    kcnt = K / gridDim.z;
    kbase = blockIdx.z * kcnt;
  }

  const int srow = lane >> 3;
  const int scol = ((lane & 7) ^ (srow & 7)) * 8;
  const __hip_bfloat16* Ap = A + (size_t)(m0 + wave * 8 + srow) * lda + kbase + scol;
  const __hip_bfloat16* Bpb = nullptr;
  const float* Bpf = nullptr;
  if constexpr (BF32)
    Bpf = (const float*)Bx;
  else
    Bpb = (const __hip_bfloat16*)Bx + (size_t)(n0 + wave * 8 + srow) * ldb + kbase + scol;

  f32x4 acc[4][4] = {};

  for (int k0 = 0; k0 < kcnt; k0 += BK) {
    __syncthreads();
#pragma unroll
    for (int u = 0; u < 4; ++u) {
      __builtin_amdgcn_global_load_lds(
          (const AS1 void*)(Ap + (size_t)(u * 32) * lda + k0),
          (AS3 void*)(&As[(u * 32 + wave * 8) * BK]), 16, 0, 0);
      if constexpr (!BF32)
        __builtin_amdgcn_global_load_lds(
            (const AS1 void*)(Bpb + (size_t)(u * 32) * ldb + k0),
            (AS3 void*)(&Bs[(u * 32 + wave * 8) * BK]), 16, 0, 0);
    }
    if constexpr (BF32) {
#pragma unroll
      for (int u = 0; u < 4; ++u) {
        int c = u * 256 + tid;
        int row = c >> 3, kc = c & 7;
        const float* src = Bpf + (size_t)(n0 + row) * ldb + kbase + k0 + kc * 8;
        float4 f0 = *(const float4*)src;
        float4 f1 = *(const float4*)(src + 4);
        bf16_8 bv;
        bv[0] = (__bf16)f0.x; bv[1] = (__bf16)f0.y; bv[2] = (__bf16)f0.z; bv[3] = (__bf16)f0.w;
        bv[4] = (__bf16)f1.x; bv[5] = (__bf16)f1.y; bv[6] = (__bf16)f1.z; bv[7] = (__bf16)f1.w;
        *(bf16_8*)(&Bs[row * LDBP + kc * 8]) = bv;
      }
    }
    __syncthreads();
#pragma unroll
    for (int kk = 0; kk < 2; ++kk) {
      bf16_8 af[4], bfr[4];
#pragma unroll
      for (int i = 0; i < 4; ++i)
        af[i] = *(const bf16_8*)(
            &As[(wm + i * 16 + l16) * BK + (((kk * 4 + quad) ^ (l16 & 7)) * 8)]);
#pragma unroll
      for (int j = 0; j < 4; ++j) {
        if constexpr (BF32)
          bfr[j] = *(const bf16_8*)(&Bs[(wn + j * 16 + l16) * LDBP + kk * 32 + quad * 8]);
        else
          bfr[j] = *(const bf16_8*)(
              &Bs[(wn + j * 16 + l16) * BK + (((kk * 4 + quad) ^ (l16 & 7)) * 8)]);
      }
#pragma unroll
      for (int i = 0; i < 4; ++i)
#pragma unroll
        for (int j = 0; j < 4; ++j)
          acc[i][j] =
              __builtin_amdgcn_mfma_f32_16x16x32_bf16(af[i], bfr[j], acc[i][j], 0, 0, 0);
    }
  }

#pragma unroll
  for (int i = 0; i < 4; ++i) {
#pragma unroll
    for (int j = 0; j < 4; ++j) {
#pragma unroll
      for (int r = 0; r < 4; ++r) {
        const int row = m0 + wm + i * 16 + quad * 4 + r;
        const int col = n0 + wn + j * 16 + l16;
        const float v = acc[i][j][r];
        if constexpr (MODE == 0) {
          const int tsel = n0 / 768;
          const size_t idx = ((size_t)tsel * M + row) * 768 + (col - tsel * 768);
          const float vs = (tsel == 0) ? v * SCL_Q : v;  // pre-scale Q slot
          ((__hip_bfloat16*)out)[idx] = __hip_bfloat16(vs);
        } else if constexpr (MODE == 1) {
          float tt = v + bias[col];
          float gl = 0.5f * tt * (1.0f + erff(tt * 0.70710678118654752f));
          ((__hip_bfloat16*)out)[(size_t)row * ldout + col] = __hip_bfloat16(gl);
        } else if constexpr (MODE == 2) {
          float add = v + ((blockIdx.z == 0 && bias) ? bias[col] : 0.f);
          atomicAdd((float*)out + (size_t)row * 768 + col, add);
        } else {
          ((float*)out)[(size_t)blockIdx.z * M * 768 + (size_t)row * 768 + col] = v;
        }
      }
    }
  }
}

// ---------------------------------------------------------------- attn-proj 64x64-tile direct GEMM
// res = x + A@B^T + bias, z=1 (each output owned by one block -> plain stores,
// no partials/atomics). N=768 -> grid (12,64) = 768 blocks; LDS 16KB.
__global__ __launch_bounds__(256) void gemm_proj64(
    const __hip_bfloat16* __restrict__ A, const __hip_bfloat16* __restrict__ B,
    const float* __restrict__ x, const float* __restrict__ bias,
    float* __restrict__ res) {
  constexpr int BK = 64;
  const int K = 768;
  __shared__ __align__(16) __bf16 As[64 * BK];
  __shared__ __align__(16) __bf16 Bs[64 * BK];
  const int tid = threadIdx.x;
  const int m0 = blockIdx.y * 64;
  const int n0 = blockIdx.x * 64;
  const int wave = tid >> 6;
  const int lane = tid & 63;
  const int quad = lane >> 4;
  const int l16 = lane & 15;
  const int wm = (wave & 1) * 32;
  const int wn = (wave >> 1) * 32;

  const int srow = lane >> 3;
  const int scol = ((lane & 7) ^ (srow & 7)) * 8;
  const __hip_bfloat16* Ap = A + (size_t)(m0 + srow) * K + scol;
  const __hip_bfloat16* Bp = B + (size_t)(n0 + srow) * K + scol;

  f32x4 acc[2][2] = {};

  for (int k0 = 0; k0 < K; k0 += BK) {
    __syncthreads();
#pragma unroll
    for (int u = 0; u < 2; ++u) {
      const int rr = u * 32 + wave * 8;  // 4 waves x 2 = rows 0..63
      __builtin_amdgcn_global_load_lds(
          (const AS1 void*)(Ap + (size_t)rr * K + k0),
          (AS3 void*)(&As[rr * BK]), 16, 0, 0);
      __builtin_amdgcn_global_load_lds(
          (const AS1 void*)(Bp + (size_t)rr * K + k0),
          (AS3 void*)(&Bs[rr * BK]), 16, 0, 0);
    }
    __syncthreads();
#pragma unroll
    for (int kk = 0; kk < 2; ++kk) {
      bf16_8 af[2], bfr[2];
#pragma unroll
      for (int i = 0; i < 2; ++i)
        af[i] = *(const bf16_8*)(
            &As[(wm + i * 16 + l16) * BK + (((kk * 4 + quad) ^ (l16 & 7)) * 8)]);
#pragma unroll
      for (int j = 0; j < 2; ++j)
        bfr[j] = *(const bf16_8*)(
            &Bs[(wn + j * 16 + l16) * BK + (((kk * 4 + quad) ^ (l16 & 7)) * 8)]);
#pragma unroll
      for (int i = 0; i < 2; ++i)
#pragma unroll
        for (int j = 0; j < 2; ++j)
          acc[i][j] =
              __builtin_amdgcn_mfma_f32_16x16x32_bf16(af[i], bfr[j], acc[i][j], 0, 0, 0);
    }
  }

#pragma unroll
  for (int i = 0; i < 2; ++i)
#pragma unroll
    for (int j = 0; j < 2; ++j)
#pragma unroll
      for (int r = 0; r < 4; ++r) {
        const int row = m0 + wm + i * 16 + quad * 4 + r;
        const int col = n0 + wn + j * 16 + l16;
        const size_t idx = (size_t)row * 768 + col;
        res[idx] = x[idx] + acc[i][j][r] + bias[col];
      }
}

// ---------------------------------------------------------------- work counter (fallback path only)
__global__ void zero_ctr(int* __restrict__ c) {
  if (threadIdx.x == 0) *c = 0;
}

// ---------------------------------------------------------------- MFMA flash attention, v6 (round-10 schedule RESTORED)
// Round-11 lesson: 8-tile chunks regressed (+30MB partial traffic, prologue
// amortized over fewer tiles). 2-way split for qblk>=16 is the measured optimum.
#define ALDP 72
__device__ __constant__ signed char UQ[48] = {
    31, 31, 30, 15, 30, 29, 29, 28, 14, 28, 27, 27, 26, 13, 26, 25,
    25, 24, 12, 24, 23, 23, 22, 11, 22, 21, 21, 20, 10, 20, 19, 19,
    18, 9, 18, 17, 17, 16, 8, 16, 7, 6, 5, 4, 3, 2, 1, 0};
__device__ __constant__ signed char UP[48] = {
    0, 1, 1, 2, 0, 0, 1, 1, 2, 0, 0, 1, 1, 2, 0, 0,
    1, 1, 2, 0, 0, 1, 1, 2, 0, 0, 1, 1, 2, 0, 0, 1,
    1, 2, 0, 0, 1, 1, 2, 0, 2, 2, 2, 2, 2, 2, 2, 2};

template <bool PRE_T, bool SPLIT>
__global__ __launch_bounds__(256) void attn_mfma(
    const __hip_bfloat16* __restrict__ qb, const __hip_bfloat16* __restrict__ kb,
    const __hip_bfloat16* __restrict__ vb, __hip_bfloat16* __restrict__ ob,
    float* __restrict__ po, float* __restrict__ pml, int* __restrict__ ctr) {
  const int S = 2048, H = 12, E = 768;
  const int tid = threadIdx.x;
  const int wave = tid >> 6;
  const int lane = tid & 63;
  const int quad = lane >> 4;
  const int l16 = lane & 15;

  __shared__ __align__(16) __bf16 Ks[64 * 64];     // single-buffer K, swizzled
  __shared__ __align__(16) __bf16 Vt[2][64 * 64];  // dbuf V^T (key-permuted), swizzled
  __shared__ int task;
  __bf16* ep = &Vt[0][0] + wave * 16 * ALDP;  // epilogue buffer aliases Vt

  const int srow8 = lane >> 3;
  const int csrc = ((lane & 7) ^ srow8) * 8;
  const int NTASK = SPLIT ? 24 * 48 : 24 * 32;

  for (;;) {
    if (tid == 0) task = atomicAdd(ctr, 1);
    __syncthreads();
    const int t = task;
    if (t >= NTASK) return;
    int qblk, part, bh;
    if constexpr (SPLIT) {
      const int unit = t / 24;
      bh = t - unit * 24;
      qblk = UQ[unit];
      part = UP[unit];
    } else {
      qblk = 31 - (t / 24);
      bh = t - (t / 24) * 24;
      part = 2;
    }
    const int b = bh / H, h = bh - b * H;
    const int q0 = qblk * 64;
    const int qw = q0 + wave * 16;
    const size_t base = (size_t)b * S * E + (size_t)h * 64;
    const int mid = (qblk + 1) >> 1;
    const int kbgn = (part == 1) ? mid : 0;
    const int kend = (part == 0) ? mid : qblk + 1;

    auto STAGE_K = [&](int kts) {
      const int k0s = kts * 64;
#pragma unroll
      for (int u = 0; u < 2; ++u) {
        const int trow = wave * 16 + u * 8;
        __builtin_amdgcn_global_load_lds(
            (const AS1 void*)(kb + base + (size_t)(k0s + trow + srow8) * E + csrc),
            (AS3 void*)(&Ks[trow * 64]), 16, 0, 0);
      }
    };
    auto STAGE_V = [&](int kts, int buf) {
      const int k0s = kts * 64;
      if constexpr (PRE_T) {
#pragma unroll
        for (int u = 0; u < 2; ++u) {
          const int trow = wave * 16 + u * 8;
          __builtin_amdgcn_global_load_lds(
              (const AS1 void*)(vb + ((size_t)(bh * 64 + trow + srow8)) * S + k0s + csrc),
              (AS3 void*)(&Vt[buf][trow * 64]), 16, 0, 0);
        }
      } else {
#pragma unroll
        for (int u = 0; u < 2; ++u) {
          int i = tid + u * 256;
          int kr = i & 63, dq = i >> 6;
          bf16_8 vv = *(const bf16_8*)(vb + base + (size_t)(k0s + kr) * E + dq * 8);
          const int c = 32 * (kr >> 5) + 8 * ((kr >> 2) & 3) + 4 * ((kr >> 4) & 1) + (kr & 3);
#pragma unroll
          for (int j = 0; j < 8; ++j) {
            int drow = dq * 8 + j;
            Vt[buf][drow * 64 + (((c >> 3) ^ (drow & 7)) * 8) + (c & 7)] = vv[j];
          }
        }
      }
    };

    bf16_8 qf[2];
#pragma unroll
    for (int s = 0; s < 2; ++s)
      qf[s] = *(const bf16_8*)(qb + base + (size_t)(qw + l16) * E + s * 32 + quad * 8);

    f32x4 o[4] = {};
    float mq = -1e30f, lq = 0.f;

    STAGE_K(kbgn);
    STAGE_V(kbgn, 0);
    __syncthreads();
    int cur = 0;

    for (int kt = kbgn; kt < kend; ++kt) {
      const int k0 = kt * 64;

      // S^T = K·Q^T (already exp2-domain-scaled via Q)
      f32x4 sc[4] = {};
      __builtin_amdgcn_s_setprio(1);
#pragma unroll
      for (int jj = 0; jj < 4; ++jj)
#pragma unroll
        for (int s = 0; s < 2; ++s) {
          bf16_8 kf = *(const bf16_8*)(
              &Ks[(jj * 16 + l16) * 64 + (((s * 4 + quad) ^ (l16 & 7)) * 8)]);
          sc[jj] = __builtin_amdgcn_mfma_f32_16x16x32_bf16(kf, qf[s], sc[jj], 0, 0, 0);
        }
      __builtin_amdgcn_s_setprio(0);

      __syncthreads();  // #1: all waves done reading Ks
      if (kt + 1 < kend) {
        STAGE_K(kt + 1);
        STAGE_V(kt + 1, cur ^ 1);
      }

      // causal mask on diagonal tile only
      if (kt == qblk) {
#pragma unroll
        for (int jj = 0; jj < 4; ++jj)
#pragma unroll
          for (int r = 0; r < 4; ++r)
            if ((k0 + jj * 16 + quad * 4 + r) > (qw + l16)) sc[jj][r] = -1e30f;
      }
      // per-query tile max (tree + 2 shuffles)
      float mj[4];
#pragma unroll
      for (int jj = 0; jj < 4; ++jj)
        mj[jj] = fmaxf(fmaxf(sc[jj][0], sc[jj][1]), fmaxf(sc[jj][2], sc[jj][3]));
      float pmax = fmaxf(fmaxf(mj[0], mj[1]), fmaxf(mj[2], mj[3]));
      pmax = fmaxf(pmax, __shfl_xor(pmax, 16));
      pmax = fmaxf(pmax, __shfl_xor(pmax, 32));
      // defer-max: only rescale when some lane's max rose past mq + 11.5 bits
      if (!__all(pmax <= mq + 11.5f)) {
        const float mn = fmaxf(mq, pmax);
        const float corr = exp2f(mq - mn);
        mq = mn;
        lq *= corr;
#pragma unroll
        for (int nt2 = 0; nt2 < 4; ++nt2)
#pragma unroll
          for (int r = 0; r < 4; ++r) o[nt2][r] *= corr;
      }
      // exp2 + tree sum
      float sj[4];
#pragma unroll
      for (int jj = 0; jj < 4; ++jj) {
#pragma unroll
        for (int r = 0; r < 4; ++r) sc[jj][r] = exp2f(sc[jj][r] - mq);
        sj[jj] = (sc[jj][0] + sc[jj][1]) + (sc[jj][2] + sc[jj][3]);
      }
      float sum = (sj[0] + sj[1]) + (sj[2] + sj[3]);
      sum += __shfl_xor(sum, 16);
      sum += __shfl_xor(sum, 32);
      lq += sum;

      // P fragments in-register (key-permuted to match vt layout)
      bf16_8 pf[2];
#pragma unroll
      for (int s = 0; s < 2; ++s)
#pragma unroll
        for (int r = 0; r < 4; ++r) {
          pf[s][r] = (__bf16)sc[2 * s][r];
          pf[s][4 + r] = (__bf16)sc[2 * s + 1][r];
        }

      // O^T += V^T·P^T
      __builtin_amdgcn_s_setprio(1);
#pragma unroll
      for (int s = 0; s < 2; ++s)
#pragma unroll
        for (int dt = 0; dt < 4; ++dt) {
          bf16_8 vf = *(const bf16_8*)(
              &Vt[cur][(dt * 16 + l16) * 64 + (((s * 4 + quad) ^ (l16 & 7)) * 8)]);
          o[dt] = __builtin_amdgcn_mfma_f32_16x16x32_bf16(vf, pf[s], o[dt], 0, 0, 0);
        }
      __builtin_amdgcn_s_setprio(0);

      __syncthreads();  // #2: drains K/V staging; Vt[cur] free
      cur ^= 1;
    }

    if (SPLIT && part != 2) {
      const int cidx = bh * 16 + (qblk - 16);
      float* poT = po + (size_t)cidx * 8192 + part * 4096;
      const int ql = wave * 16 + l16;
#pragma unroll
      for (int dt = 0; dt < 4; ++dt)
#pragma unroll
        for (int r = 0; r < 4; ++r)
          poT[(dt * 16 + quad * 4 + r) * 64 + ql] = o[dt][r];
      if (quad == 0) {
        pml[(size_t)cidx * 256 + part * 128 + ql] = mq;
        pml[(size_t)cidx * 256 + part * 128 + 64 + ql] = lq;
      }
    } else {
      const float inv = 1.f / lq;
#pragma unroll
      for (int dt = 0; dt < 4; ++dt) {
        bf16_4 o4;
#pragma unroll
        for (int r = 0; r < 4; ++r) o4[r] = (__bf16)(o[dt][r] * inv);
        *(bf16_4*)(&ep[l16 * ALDP + dt * 16 + quad * 4]) = o4;
      }
#pragma unroll
      for (int u = 0; u < 2; ++u) {
        int j = lane + u * 64;
        int ql = j >> 3, ch = j & 7;
        bf16_8 ov = *(const bf16_8*)(&ep[ql * ALDP + ch * 8]);
        *(bf16_8*)(ob + base + (size_t)(qw + ql) * E + ch * 8) = ov;
      }
    }
  }
}

// ---------------------------------------------------------------- combine split-KV partials (coalesced, np=2)
__global__ __launch_bounds__(256) void attn_combine(
    const float* __restrict__ po, const float* __restrict__ pml,
    __hip_bfloat16* __restrict__ ob) {
  const int S = 2048, H = 12, E = 768;
  const int cidx = blockIdx.x;
  const int bh = cidx >> 4;
  const int qblk = 16 + (cidx & 15);
  const int b = bh / H, h = bh - b * H;
  const int q0 = qblk * 64;
  const size_t base = (size_t)b * S * E + (size_t)h * 64;
  const float* P0 = po + (size_t)cidx * 8192;
  const float* P1 = P0 + 4096;
  const float* ML = pml + (size_t)cidx * 256;

  __shared__ float a1[64], a2[64], dn[64];
  __shared__ float T[64 * 65];
  const int t = threadIdx.x;
  if (t < 64) {
    const float m1 = ML[t], l1 = ML[64 + t];
    const float m2 = ML[128 + t], l2 = ML[192 + t];
    const float ms = fmaxf(m1, m2);
    const float e1 = exp2f(m1 - ms), e2 = exp2f(m2 - ms);
    a1[t] = e1;
    a2[t] = e2;
    dn[t] = 1.f / (e1 * l1 + e2 * l2);
  }
  __syncthreads();
  const int q = t & 63;
  const int w = t >> 6;
#pragma unroll
  for (int i = 0; i < 16; ++i) {
    const int d = w * 16 + i;
    T[q * 65 + d] = (a1[q] * P0[d * 64 + q] + a2[q] * P1[d * 64 + q]) * dn[q];
  }
  __syncthreads();
  const int c8 = t & 7;
  const int qr = t >> 3;
#pragma unroll
  for (int p = 0; p < 2; ++p) {
    const int qq = qr + p * 32;
    bf16_8 ov;
#pragma unroll
    for (int j = 0; j < 8; ++j) ov[j] = (__bf16)T[qq * 65 + c8 * 8 + j];
    *(bf16_8*)(ob + base + (size_t)(q0 + qq) * E + c8 * 8) = ov;
  }
}

// ---------------------------------------------------------------- launch
extern "C" void kernel_launch(void* const* d_in, const int* in_sizes, int n_in,
                              void* d_out, int out_size, void* d_ws, size_t ws_size,
                              hipStream_t stream) {
  const int Bv = 2, S = 2048, E = 768, FF = 3072;
  const int M = Bv * S;  // 4096
  const size_t ME = (size_t)M * E;
  const size_t EE = (size_t)E * E;
  const size_t EF = (size_t)E * FF;

  const float* x = (const float*)d_in[0];
  const float* wq = (const float*)d_in[1];
  const float* wk = (const float*)d_in[2];
  const float* wv = (const float*)d_in[3];
  const float* wo = (const float*)d_in[4];
  const float* bo = (const float*)d_in[5];
  const float* w1 = (const float*)d_in[6];
  const float* b1 = (const float*)d_in[7];
  const float* w2 = (const float*)d_in[8];
  const float* b2 = (const float*)d_in[9];
  const float* gamma = (const float*)d_in[10];
  const float* beta = (const float*)d_in[11];

  // ws: [ctr+256B][s0..s4: 5×ME bf16][s5: w1|w2 bf16 2×EF][pp: 4×ME fp32 = 50.3MB]
  // Attention phase time-shares pp: vt (6.29MB) + po (384×32KB = 12.6MB) + pml (0.39MB).
  int* ctr = (int*)d_ws;
  __hip_bfloat16* slot = (__hip_bfloat16*)((char*)d_ws + 256);
  __hip_bfloat16* s0 = slot;
  __hip_bfloat16* s1 = slot + ME;
  __hip_bfloat16* s4 = slot + 4 * ME;
  __hip_bfloat16* s5 = slot + 5 * ME;
  float* pp = (float*)(slot + 5 * ME + 2 * EF);
  __hip_bfloat16* vt = (__hip_bfloat16*)pp;
  float* po = (float*)((char*)pp + ME * sizeof(__hip_bfloat16));
  float* pml = po + (size_t)384 * 8192;
  float* res = (float*)d_out;

  const size_t need_mid = 256 + (5 * ME + 2 * EF) * sizeof(__hip_bfloat16);
  const size_t need_full = need_mid + 4 * ME * sizeof(float);
  const bool full = ws_size >= need_full;
  const bool mid = ws_size >= need_mid;

  // 0. weights -> bf16 (one launch when s5 exists)
  if (mid)
    cvt_all<<<6912, 256, 0, stream>>>(wq, wk, wv, wo, w1, w2, s4, s5);
  else
    cvt_multi<<<dim3(EE / 1024, 4), 256, 0, stream>>>(
        wq, wk, wv, wo, s4, s4 + EE, s4 + 2 * EE, s4 + 3 * EE);
  // 1. LN1
  ln_kernel<<<M, 256, 0, stream>>>(x, gamma, beta, s0, E);
  // 2. fused Q/K/V projection -> s1,s2,s3 (Q pre-scaled by SCL_Q)
  gemm_bt<0, false><<<dim3(18, 32), 256, 0, stream>>>(s0, s4, nullptr, s1, M, 2304, E, E, E, 0);
  // 3. causal flash attention -> s0 (2-way KV split -> po/pml, combined after)
  if (full) {
    transpose_v<<<dim3(32, 24), 256, 0, stream>>>(s1 + 2 * ME, vt, ctr);  // also zeroes ctr
    attn_mfma<true, true><<<1152, 256, 0, stream>>>(s1, s1 + ME, vt, s0, po, pml, ctr);
    attn_combine<<<384, 256, 0, stream>>>(po, pml, s0);
  } else {
    zero_ctr<<<1, 64, 0, stream>>>(ctr);
    attn_mfma<false, false><<<768, 256, 0, stream>>>(
        s1, s1 + ME, s1 + 2 * ME, s0, nullptr, nullptr, ctr);
  }

  if (full) {
    // 4. attn-proj DIRECT: res = x + attn@wo^T + bo (64² tile, z=1, no partials)
    gemm_proj64<<<dim3(12, 64), 256, 0, stream>>>(s0, s4 + 3 * EE, x, bo, res);
    // 5. y = LN2(res) -> s0
    ln_kernel<<<M, 256, 0, stream>>>(res, gamma, beta, s0, E);
    // 6. FFN up + GELU -> s1..s4
    gemm_bt<1, false><<<dim3(24, 32), 256, 0, stream>>>(s0, s5, b1, s1, M, FF, E, E, E, FF);
    // 7. FFN down partials z=4
    gemm_bt<3, false><<<dim3(6, 32, 4), 256, 0, stream>>>(
        s1, s5 + EF, nullptr, pp, M, E, FF, FF, FF, 0);
    // 8. out = res + Σpp + b2
    reduce_out<<<M, 256, 0, stream>>>(pp, 4, b2, res);
  } else {
    hipMemcpyAsync(d_out, x, ME * sizeof(float), hipMemcpyDeviceToDevice, stream);
    gemm_bt<2, false><<<dim3(6, 32, 2), 256, 0, stream>>>(
        s0, s4 + 3 * EE, bo, res, M, E, E, E, E, 0);
    ln_kernel<<<M, 256, 0, stream>>>(res, gamma, beta, s0, E);
    if (mid) {
      gemm_bt<1, false><<<dim3(24, 32), 256, 0, stream>>>(s0, s5, b1, s1, M, FF, E, E, E, FF);
      gemm_bt<2, false><<<dim3(6, 32, 4), 256, 0, stream>>>(
          s1, s5 + EF, b2, res, M, E, FF, FF, FF, 0);
    } else {
      gemm_bt<1, true><<<dim3(24, 32), 256, 0, stream>>>(s0, w1, b1, s1, M, FF, E, E, E, FF);
      cvt_multi<<<dim3(EF / 1024, 1), 256, 0, stream>>>(
          w2, nullptr, nullptr, nullptr, s0, nullptr, nullptr, nullptr);
      gemm_bt<2, false><<<dim3(6, 32, 4), 256, 0, stream>>>(
          s1, s0, b2, res, M, E, FF, FF, FF, 0);
    }
  }
}